// Round 14
// baseline (3337.135 us; speedup 1.0000x reference)
//
#include <hip/hip_runtime.h>
#include <hip/hip_bf16.h>

typedef unsigned long long ull;

#define THREADS 1024
#define NWAVE 16
#define MAXG 1280           // max 16-pt groups supported (n <= 20480)

// ---------------- DPP helpers (rounds 5-13 validated) ---------------------
template<int CTRL, int RM>
__device__ __forceinline__ float fmax_dpp(float v) {
    int s = __builtin_amdgcn_update_dpp(__float_as_int(v), __float_as_int(v), CTRL, RM, 0xf, false);
    return fmaxf(v, __int_as_float(s));
}
template<int CTRL, int RM>
__device__ __forceinline__ float fmin_dpp(float v) {
    int s = __builtin_amdgcn_update_dpp(__float_as_int(v), __float_as_int(v), CTRL, RM, 0xf, false);
    return fminf(v, __int_as_float(s));
}
template<int CTRL, int RM>
__device__ __forceinline__ int imin_dpp(int v) {
    int s = __builtin_amdgcn_update_dpp(v, v, CTRL, RM, 0xf, false);
    return (s < v) ? s : v;
}
template<int CTRL, int RM>
__device__ __forceinline__ ull kmax_dpp(ull k) {
    unsigned hi = (unsigned)(k >> 32), lo = (unsigned)k;
    unsigned hi2 = (unsigned)__builtin_amdgcn_update_dpp((int)hi, (int)hi, CTRL, RM, 0xf, false);
    unsigned lo2 = (unsigned)__builtin_amdgcn_update_dpp((int)lo, (int)lo, CTRL, RM, 0xf, false);
    ull k2 = ((ull)hi2 << 32) | lo2;
    return (k2 > k) ? k2 : k;
}
// 16-lane ROW reduces: lane15 of each row = row total
__device__ __forceinline__ float row_fmax(float v) {
    v = fmax_dpp<0x111,0xf>(v); v = fmax_dpp<0x112,0xf>(v);
    v = fmax_dpp<0x114,0xf>(v); v = fmax_dpp<0x118,0xf>(v);
    return v;
}
__device__ __forceinline__ float row_fmin(float v) {
    v = fmin_dpp<0x111,0xf>(v); v = fmin_dpp<0x112,0xf>(v);
    v = fmin_dpp<0x114,0xf>(v); v = fmin_dpp<0x118,0xf>(v);
    return v;
}
__device__ __forceinline__ int row_imin(int v) {
    v = imin_dpp<0x111,0xf>(v); v = imin_dpp<0x112,0xf>(v);
    v = imin_dpp<0x114,0xf>(v); v = imin_dpp<0x118,0xf>(v);
    return v;
}
__device__ __forceinline__ float wave_fmax(float v) {
    v = row_fmax(v);
    v = fmax_dpp<0x142,0xa>(v); v = fmax_dpp<0x143,0xc>(v);
    return v;                       // total in lane 63
}
__device__ __forceinline__ float wave_fmin(float v) {
    v = row_fmin(v);
    v = fmin_dpp<0x142,0xa>(v); v = fmin_dpp<0x143,0xc>(v);
    return v;
}
__device__ __forceinline__ ull wave_kmax(ull k) {
    k = kmax_dpp<0x111,0xf>(k); k = kmax_dpp<0x112,0xf>(k);
    k = kmax_dpp<0x114,0xf>(k); k = kmax_dpp<0x118,0xf>(k);
    k = kmax_dpp<0x142,0xa>(k); k = kmax_dpp<0x143,0xc>(k);
    return k;
}
__device__ __forceinline__ int morton4(int x, int y, int z) {
    int r = 0;
#pragma unroll
    for (int k = 0; k < 4; ++k)
        r |= ((x >> k & 1) << (3 * k)) | ((y >> k & 1) << (3 * k + 1)) | ((z >> k & 1) << (3 * k + 2));
    return r;
}
__device__ __forceinline__ int cellof(float x, float y, float z,
                                      float bx, float by, float bz,
                                      float ivx, float ivy, float ivz) {
    int ix = (int)((x - bx) * ivx); ix = ix < 0 ? 0 : (ix > 15 ? 15 : ix);
    int iy = (int)((y - by) * ivy); iy = iy < 0 ? 0 : (iy > 15 ? 15 : iy);
    int iz = (int)((z - bz) * ivz); iz = iz < 0 ? 0 : (iz > 15 ? 15 : iz);
    return morton4(ix, iy, iz);
}

// LDS fixed-region byte offsets (MAXG=1280 spacing; dist follows at FIXED)
#define OFS_GKEY 0          // MAXG * ull      (10240)
#define OFS_GWIN 10240      // MAXG * float4   (20480)
#define OFS_GMAX 30720      // MAXG * f32      (5120)
#define OFS_CX   35840
#define OFS_CY   40960
#define OFS_CZ   46080
#define OFS_EX   51200
#define OFS_EY   56320
#define OFS_EZ   61440
#define OFS_LIST 66560      // MAXG * u16      (2560)
#define OFS_PART 69120      // 32 * ull
#define OFS_MISC 69376      // 32 * int ([0]=count, [8..23]=P3 scan)
#define OFS_RED  69504      // 96 * f32
#define FIXED_BYTES 69888

// Exact grouped lazy-prune FPS, 16-pt groups (tight AABBs), r11 skeleton:
// per iter: A (prune vs winner, 2-sweep, ballot-compact) -> bar -> C (update
// listed groups, 4 groups/wave-pass via 16-lane row reduces) -> bar -> D1
// (per-wave key max, 2 keys/thread) -> bar -> D2 (combine partials, decode
// winner, uniform s_gwin read for coords).
// Skipped-group invariant: lb2 <= min_p d(p,c)^2 (conservative slack);
// prune iff lb2 >= gmax >= dist_p -> no dist changes. Exactness never
// depends on bound quality, only the conservative direction.
// Key = (distbits<<26)|((0x7fff-orig)<<11)|g: max dist, then MIN original
// index (np.argmax first-occurrence); g-bits break only impossible ties.
__global__ __launch_bounds__(THREADS)
void fps_grouped(const float* __restrict__ C, float4* __restrict__ gxyzo,
                 int n, int m, int G16, int* __restrict__ idx_out) {
    const int b = blockIdx.x;
    const int t = threadIdx.x;
    const int lane = t & 63;
    const int wid  = t >> 6;
    const int row  = lane >> 4;        // 0..3
    const int s16  = lane & 15;
    const int GP = G16 * 16;
    const float* __restrict__ P = C + (size_t)b * n * 3;
    float4* __restrict__ gx = gxyzo + (size_t)b * GP;

    extern __shared__ char smem[];
    ull*    s_gkey = (ull*)(smem + OFS_GKEY);
    float4* s_gwin = (float4*)(smem + OFS_GWIN);
    float*  s_gmax = (float*)(smem + OFS_GMAX);
    float*  s_cx   = (float*)(smem + OFS_CX);
    float*  s_cy   = (float*)(smem + OFS_CY);
    float*  s_cz   = (float*)(smem + OFS_CZ);
    float*  s_ex   = (float*)(smem + OFS_EX);
    float*  s_ey   = (float*)(smem + OFS_EY);
    float*  s_ez   = (float*)(smem + OFS_EZ);
    unsigned short* s_list = (unsigned short*)(smem + OFS_LIST);
    ull*    s_part = (ull*)(smem + OFS_PART);
    int*    s_misc = (int*)(smem + OFS_MISC);
    float*  s_red  = (float*)(smem + OFS_RED);
    float*  s_dist = (float*)(smem + FIXED_BYTES);
    unsigned* s_hist = (unsigned*)s_dist;        // alias, preproc only

    // ---- P1: bbox ----
    float mnx = 1e30f, mny = 1e30f, mnz = 1e30f;
    float mxx = -1e30f, mxy = -1e30f, mxz = -1e30f;
    for (int g = t; g < n; g += THREADS) {
        float x = P[3 * g], y = P[3 * g + 1], z = P[3 * g + 2];
        mnx = fminf(mnx, x); mxx = fmaxf(mxx, x);
        mny = fminf(mny, y); mxy = fmaxf(mxy, y);
        mnz = fminf(mnz, z); mxz = fmaxf(mxz, z);
    }
    mnx = wave_fmin(mnx); mny = wave_fmin(mny); mnz = wave_fmin(mnz);
    mxx = wave_fmax(mxx); mxy = wave_fmax(mxy); mxz = wave_fmax(mxz);
    if (lane == 63) {
        s_red[wid * 6 + 0] = mnx; s_red[wid * 6 + 1] = mny; s_red[wid * 6 + 2] = mnz;
        s_red[wid * 6 + 3] = mxx; s_red[wid * 6 + 4] = mxy; s_red[wid * 6 + 5] = mxz;
    }
    __syncthreads();
    if (t == 0) {
        float a0 = 1e30f, a1 = 1e30f, a2 = 1e30f, b0 = -1e30f, b1 = -1e30f, b2 = -1e30f;
        for (int w = 0; w < NWAVE; ++w) {
            a0 = fminf(a0, s_red[w * 6 + 0]); a1 = fminf(a1, s_red[w * 6 + 1]);
            a2 = fminf(a2, s_red[w * 6 + 2]); b0 = fmaxf(b0, s_red[w * 6 + 3]);
            b1 = fmaxf(b1, s_red[w * 6 + 4]); b2 = fmaxf(b2, s_red[w * 6 + 5]);
        }
        s_red[0] = a0; s_red[1] = a1; s_red[2] = a2;
        s_red[3] = 15.9999f / (b0 - a0 + 1e-20f);
        s_red[4] = 15.9999f / (b1 - a1 + 1e-20f);
        s_red[5] = 15.9999f / (b2 - a2 + 1e-20f);
    }
    __syncthreads();
    const float bx = s_red[0], by = s_red[1], bz = s_red[2];
    const float ivx = s_red[3], ivy = s_red[4], ivz = s_red[5];

    // ---- P2: histogram ----
    for (int i = t; i < 4096; i += THREADS) s_hist[i] = 0;
    __syncthreads();
    for (int g = t; g < n; g += THREADS) {
        float x = P[3 * g], y = P[3 * g + 1], z = P[3 * g + 2];
        atomicAdd(&s_hist[cellof(x, y, z, bx, by, bz, ivx, ivy, ivz)], 1u);
    }
    __syncthreads();

    // ---- P3: exclusive scan over 4096 cells ----
    {
        unsigned c0 = s_hist[4 * t], c1 = s_hist[4 * t + 1];
        unsigned c2 = s_hist[4 * t + 2], c3 = s_hist[4 * t + 3];
        unsigned sum4 = c0 + c1 + c2 + c3;
        unsigned incl = sum4;
        for (int off = 1; off < 64; off <<= 1) {
            unsigned u = (unsigned)__shfl_up((int)incl, off);
            if (lane >= off) incl += u;
        }
        if (lane == 63) s_misc[8 + wid] = (int)incl;
        __syncthreads();
        unsigned woff = 0;
        for (int w = 0; w < wid; ++w) woff += (unsigned)s_misc[8 + w];
        unsigned base = woff + incl - sum4;
        s_hist[4 * t]     = base;
        s_hist[4 * t + 1] = base + c0;
        s_hist[4 * t + 2] = base + c0 + c1;
        s_hist[4 * t + 3] = base + c0 + c1 + c2;
    }
    __syncthreads();

    // ---- P4: scatter (sorted coords + orig idx in .w) ----
    for (int g = t; g < n; g += THREADS) {
        float x = P[3 * g], y = P[3 * g + 1], z = P[3 * g + 2];
        unsigned pos = atomicAdd(&s_hist[cellof(x, y, z, bx, by, bz, ivx, ivy, ivz)], 1u);
        gx[pos] = make_float4(x, y, z, (float)g);
    }
    __syncthreads();

    // ---- P5: per-16-pt-group AABB metadata + init (4 groups per wave) ----
    for (int gb = wid; gb * 4 < G16; gb += NWAVE) {
        int g = gb * 4 + row;
        bool gvalid = g < G16;
        int base = g * 16;
        int cnt = gvalid ? (n - base < 16 ? n - base : 16) : 0;
        bool memb = gvalid && (s16 < cnt);
        float4 w = make_float4(0.f, 0.f, 0.f, 0.f);
        if (memb) w = gx[base + s16];
        float xn = memb ? w.x : 1e30f, xx = memb ? w.x : -1e30f;
        float yn = memb ? w.y : 1e30f, yx = memb ? w.y : -1e30f;
        float zn = memb ? w.z : 1e30f, zx = memb ? w.z : -1e30f;
        xn = __shfl(row_fmin(xn), lane | 15); xx = __shfl(row_fmax(xx), lane | 15);
        yn = __shfl(row_fmin(yn), lane | 15); yx = __shfl(row_fmax(yx), lane | 15);
        zn = __shfl(row_fmin(zn), lane | 15); zx = __shfl(row_fmax(zx), lane | 15);
        if (gvalid && s16 == 0) {
            s_cx[g] = (xn + xx) * 0.5f; s_ex[g] = (xx - xn) * 0.5f + 1e-7f;
            s_cy[g] = (yn + yx) * 0.5f; s_ey[g] = (yx - yn) * 0.5f + 1e-7f;
            s_cz[g] = (zn + zx) * 0.5f; s_ez[g] = (zx - zn) * 0.5f + 1e-7f;
            s_gmax[g] = 1e10f;          // forces iter-1 update of every group
        }
        if (gvalid) {
            if (!memb) gx[base + s16] = make_float4(0.f, 0.f, 0.f, 0.f);
            s_dist[base + s16] = memb ? 1e10f : -1.0f;
        }
    }
    for (int i = G16 + t; i < MAXG; i += THREADS) s_gkey[i] = 0;
    if (t == 0) { s_misc[0] = 0; idx_out[(size_t)b * m] = 0; }
    __syncthreads();

    // ---- main loop: A -> bar -> C -> bar -> D1 -> bar -> D2 ----
    float lx = P[0], ly = P[1], lz = P[2];
    const size_t iobase = (size_t)b * m;
    for (int it = 1; it < m; ++it) {
        const int par = (it & 1) * 16;

        // Phase A: AABB prune test, 2 strided sweeps, ballot-compacted list
        for (int g = t; g < G16; g += THREADS) {
            float gmax = s_gmax[g];
            float ax = fmaxf(fabsf(lx - s_cx[g]) - s_ex[g], 0.0f);
            float ay = fmaxf(fabsf(ly - s_cy[g]) - s_ey[g], 0.0f);
            float az = fmaxf(fabsf(lz - s_cz[g]) - s_ez[g], 0.0f);
            float lb2 = ax * ax + ay * ay + az * az;
            bool upd = !(lb2 * 0.9999f - 1e-6f >= gmax);
            ull mask = __ballot(upd);
            if (mask) {
                int cnt = __popcll(mask);
                int base = 0;
                if (lane == 0) base = atomicAdd(&s_misc[0], cnt);
                base = __shfl(base, 0);
                if (upd) {
                    int pw = (int)__popcll(mask & ((1ULL << lane) - 1ULL));
                    s_list[base + pw] = (unsigned short)g;
                }
            }
        }
        __syncthreads();                       // (1)
        const int U = s_misc[0];

        // Phase C: update listed groups, 4 groups per wave-pass (row each)
        {
            const int nt = (U + 3) >> 2;
            for (int j = wid; j < nt; j += NWAVE) {
                int e = 4 * j + row;
                bool a = (e < U);
                int g = a ? (int)s_list[e] : 0;
                int o = g * 16 + s16;
                float4 w = gx[o];
                float dc = a ? s_dist[o] : -1.0f;
                float dx = __fsub_rn(w.x, lx);
                float dy = __fsub_rn(w.y, ly);
                float dz = __fsub_rn(w.z, lz);
                float d  = __fadd_rn(__fadd_rn(__fmul_rn(dx, dx), __fmul_rn(dy, dy)),
                                     __fmul_rn(dz, dz));
                float nd = fminf(dc, d);
                if (a) s_dist[o] = nd;
                float gm = __shfl(row_fmax(nd), lane | 15);   // row max bcast
                ull mask = __ballot(nd == gm);
                unsigned rm = (unsigned)(mask >> (row * 16)) & 0xffffu;
                int fl = __ffs((int)rm) - 1;                  // first matching
                int ao = __shfl((int)w.w, (lane & ~15) + fl);
                bool tie = (rm & (rm - 1u)) != 0u;
                if (__any(tie)) {                             // rare exact ties
                    int pk = (nd == gm) ? (int)w.w : 0x7FFFFFFF;
                    int mo = __shfl(row_imin(pk), lane | 15);
                    if (tie) ao = mo;
                }
                if (a && nd == gm && (int)w.w == ao)
                    s_gwin[g] = w;                            // unique lane
                if (a && s16 == 15) {
                    s_gkey[g] = ((ull)__float_as_uint(gm) << 26)
                              | ((ull)(unsigned)(0x7fff - ao) << 11)
                              | (ull)(unsigned)g;
                    s_gmax[g] = gm;
                }
            }
        }
        __syncthreads();                       // (2)

        // Phase D stage 1: per-wave max over 2 key slots per thread
        {
            ull v = s_gkey[t];
            int t2 = t + THREADS;
            if (t2 < G16) {
                ull v2 = s_gkey[t2];
                if (v2 > v) v = v2;
            }
            ull kk = wave_kmax(v);
            if (lane == 63) s_part[par + wid] = kk;
        }
        if (t == 0) s_misc[0] = 0;
        __syncthreads();                       // (3)
        // stage 2: combine 16 partials; decode group + orig
        ull k2 = s_part[par + (t & 15)];
        k2 = kmax_dpp<0x111,0xf>(k2);
        k2 = kmax_dpp<0x112,0xf>(k2);
        k2 = kmax_dpp<0x114,0xf>(k2);
        k2 = kmax_dpp<0x118,0xf>(k2);          // lane 15 = total
        unsigned klo = (unsigned)__builtin_amdgcn_readlane((int)(unsigned)k2, 15);
        int gwin = (int)(klo & 0x7ffu);
        int orig = 0x7fff - (int)((klo >> 11) & 0x7fffu);
        if (t == 0) idx_out[iobase + it] = orig;
        float4 wn = s_gwin[gwin];              // uniform LDS read
        lx = wn.x; ly = wn.y; lz = wn.z;
    }
}

// Fallback for n > 16*MAXG: exact brute force.
__global__ __launch_bounds__(1024)
void fps_brute(const float* __restrict__ C, float* __restrict__ gdist,
               int n, int m, int* __restrict__ idx_out) {
    const int b = blockIdx.x, t = threadIdx.x;
    const int lane = t & 63, wid = t >> 6;
    const float* __restrict__ P = C + (size_t)b * n * 3;
    float* __restrict__ dist = gdist + (size_t)b * n;
    __shared__ ull sp[2][16];
    for (int g = t; g < n; g += 1024) dist[g] = 1e10f;
    if (t == 0) idx_out[(size_t)b * m] = 0;
    float lx = P[0], ly = P[1], lz = P[2];
    __syncthreads();
    for (int it = 1; it < m; ++it) {
        int par = it & 1;
        ull k = 0;
        for (int g = t; g < n; g += 1024) {
            float dx = __fsub_rn(P[3 * g], lx);
            float dy = __fsub_rn(P[3 * g + 1], ly);
            float dz = __fsub_rn(P[3 * g + 2], lz);
            float d = __fadd_rn(__fadd_rn(__fmul_rn(dx, dx), __fmul_rn(dy, dy)),
                                __fmul_rn(dz, dz));
            float nd = fminf(dist[g], d);
            dist[g] = nd;
            ull kk = ((ull)__float_as_uint(nd) << 32) | (unsigned)(~g);
            if (kk > k) k = kk;
        }
        for (int off = 1; off < 64; off <<= 1) {
            ull ok = __shfl_xor(k, off);
            if (ok > k) k = ok;
        }
        if (lane == 0) sp[par][wid] = k;
        __syncthreads();
        ull kmaxv = sp[par][0];
        for (int w = 1; w < 16; ++w) { ull v = sp[par][w]; if (v > kmaxv) kmaxv = v; }
        int sbi = (int)~(unsigned)kmaxv;
        if (t == 0) idx_out[(size_t)b * m + it] = sbi;
        const float* wp = P + 3 * (size_t)(unsigned)sbi;
        lx = wp[0]; ly = wp[1]; lz = wp[2];
    }
}

__global__ void gather_kernel(const float* __restrict__ C,
                              const float* __restrict__ F,
                              const int* __restrict__ idx,
                              float* __restrict__ outC,
                              float* __restrict__ outF,
                              int n_pts, int m, int c) {
    int pair = blockIdx.x;            // b*m + s
    int b = pair / m;
    int src = idx[pair];
    size_t srcbase = (size_t)b * n_pts + src;
    const float* sF = F + srcbase * (size_t)c;
    float* dF = outF + (size_t)pair * c;
    for (int i = threadIdx.x; i < c; i += blockDim.x) dF[i] = sF[i];
    if (threadIdx.x < 3)
        outC[(size_t)pair * 3 + threadIdx.x] = C[srcbase * 3 + threadIdx.x];
}

extern "C" void kernel_launch(void* const* d_in, const int* in_sizes, int n_in,
                              void* d_out, int out_size, void* d_ws, size_t ws_size,
                              hipStream_t stream) {
    const float* C = (const float*)d_in[0];
    const float* F = (const float*)d_in[1];

    int n_total = in_sizes[0] / 3;
    int c       = in_sizes[1] / n_total;
    int bm      = out_size / (3 + c);

    int batch = 8;
    if (bm % 2000 == 0) {
        int bb = bm / 2000;
        if (bb > 0 && n_total % bb == 0 && n_total / bb >= 2000) batch = bb;
    }
    int n_pts = n_total / batch;
    int m     = (n_pts < 2000) ? n_pts : 2000;

    int* idxbuf = (int*)d_ws;
    float* outC = (float*)d_out;
    float* outF = outC + (size_t)batch * m * 3;

    int G16 = (n_pts + 15) >> 4;
    int GP  = G16 << 4;
    size_t idxbytes = (((size_t)batch * m * 4) + 255) & ~(size_t)255;
    size_t scrbytes = (size_t)batch * GP * 16;
    void* scratch;
    if (ws_size >= idxbytes + scrbytes)
        scratch = (char*)d_ws + idxbytes;
    else
        scratch = (char*)d_out + ((((size_t)out_size * 4) - scrbytes) & ~(size_t)15);

    if (G16 <= MAXG) {
        int distbytes = GP * 4; if (distbytes < 16384) distbytes = 16384;
        size_t smem = (size_t)FIXED_BYTES + distbytes;
        hipFuncSetAttribute((const void*)fps_grouped,
                            hipFuncAttributeMaxDynamicSharedMemorySize, (int)smem);
        fps_grouped<<<batch, THREADS, smem, stream>>>(C, (float4*)scratch,
                                                      n_pts, m, G16, idxbuf);
    } else {
        fps_brute<<<batch, 1024, 0, stream>>>(C, (float*)scratch, n_pts, m, idxbuf);
    }

    gather_kernel<<<batch * m, 128, 0, stream>>>(C, F, idxbuf, outC, outF,
                                                 n_pts, m, c);
}